// Round 18
// baseline (368.298 us; speedup 1.0000x reference)
//
#include <hip/hip_runtime.h>
#include <math.h>

#define LNODES 2048
#define NEDGE 16384
#define GBIG 32
#define GSM 4
#define NCOUT 256
#define BN_EPS 1e-5f
#define ND 32  // dst nodes per agg block

typedef unsigned short u16;
typedef __attribute__((ext_vector_type(8))) short bf16x8;
typedef __attribute__((ext_vector_type(4))) float f32x4;

__device__ __forceinline__ unsigned pk2(float a, float b) {  // a->lo, b->hi
  unsigned ua = __float_as_uint(a); ua += 0x7fffu + ((ua >> 16) & 1u);
  unsigned ub = __float_as_uint(b); ub += 0x7fffu + ((ub >> 16) & 1u);
  return (ua >> 16) | (ub & 0xffff0000u);
}
__device__ __forceinline__ float blo(unsigned u) { return __uint_as_float(u << 16); }
__device__ __forceinline__ float bhi(unsigned u) { return __uint_as_float(u & 0xffff0000u); }

// async global->LDS, 16B per lane. LDS dest must be wave-uniform base + lane*16.
__device__ __forceinline__ void gl16(const u16* g, u16* l) {
  __builtin_amdgcn_global_load_lds(
      (const __attribute__((address_space(1))) void*)g,
      (__attribute__((address_space(3))) void*)l, 16, 0, 0);
}

// ================= merged setup: ONE kernel =================
// blocks 0..95: weight convert (K-blocked pre-swizzled)
// blocks 96..2143: input transpose x->XT0
// block 2144: single-block CSR build (count -> scan -> dis -> fill), all in LDS.
// CSR block runs concurrently with the 2048 trans blocks; outputs consumed by agg.

struct WCvt {
  const float* src[6];
  u16* dst[6];
  int ci[6];
};

__global__ __launch_bounds__(256) void setup1_k(const int* __restrict__ ei,
                                                WCvt wp,
                                                const float* __restrict__ x_in,
                                                u16* __restrict__ XT0,
                                                int* __restrict__ rp_g,
                                                float* __restrict__ selfn_g,
                                                int* __restrict__ col,
                                                float* __restrict__ wn) {
  __shared__ float T[64][65];
  __shared__ int ldeg[LNODES];      // counts, later reused as fillc
  __shared__ int lrp[LNODES + 1];
  __shared__ float ldis[LNODES];
  __shared__ int part[256];
  const int bid = blockIdx.x;
  const int t = threadIdx.x;
  if (bid < 96) {
    // weights: W [Ci][256] f32 -> WTb[kt][ (co*32+kk) ^ ((co&7)<<3) ] bf16
    const int w = bid;
    const int bz = w >> 4;
    const int Ci = wp.ci[bz];
    const int ci0 = ((w >> 2) & 3) * 64;
    if (ci0 >= Ci) return;
    const float* W = wp.src[bz];
    u16* WT = wp.dst[bz];
    const int co0 = (w & 3) * 64;
    const int tr = t >> 4;
    const int tc = (t & 15) * 4;
#pragma unroll
    for (int p = 0; p < 4; ++p) {
      int ci = ci0 + tr + p * 16;
      float4 v = *reinterpret_cast<const float4*>(&W[(size_t)ci * NCOUT + co0 + tc]);
      T[tr + p * 16][tc + 0] = v.x; T[tr + p * 16][tc + 1] = v.y;
      T[tr + p * 16][tc + 2] = v.z; T[tr + p * 16][tc + 3] = v.w;
    }
    __syncthreads();
    const int ci = ci0 + tc;        // multiple of 4
    const int kt = ci >> 5;
    const int kk = ci & 31;         // 4-aligned -> uint2 stays aligned after XOR
#pragma unroll
    for (int p = 0; p < 4; ++p) {
      int co = co0 + tr + p * 16;
      uint2 o = {pk2(T[tc + 0][co - co0], T[tc + 1][co - co0]),
                 pk2(T[tc + 2][co - co0], T[tc + 3][co - co0])};
      size_t idx = (size_t)kt * 8192 + (unsigned)((co * 32 + kk) ^ ((co & 7) << 3));
      *reinterpret_cast<uint2*>(&WT[idx]) = o;
    }
  } else if (bid < 2144) {
    // x [G][128][L] f32 -> XT [G][L][128] bf16
    const int w = bid - 96;
    const int g = w >> 6;
    const int n0 = (w & 31) * 64;
    const int c0 = ((w >> 5) & 1) * 64;
    const int tr = t >> 4;
    const int tc = (t & 15) * 4;
#pragma unroll
    for (int p = 0; p < 4; ++p) {
      int ci = c0 + tr + p * 16;
      float4 v = *reinterpret_cast<const float4*>(&x_in[((size_t)g * 128 + ci) * LNODES + n0 + tc]);
      T[tr + p * 16][tc + 0] = v.x; T[tr + p * 16][tc + 1] = v.y;
      T[tr + p * 16][tc + 2] = v.z; T[tr + p * 16][tc + 3] = v.w;
    }
    __syncthreads();
#pragma unroll
    for (int p = 0; p < 4; ++p) {
      int nd = tr + p * 16;
      uint2 o = {pk2(T[tc + 0][nd], T[tc + 1][nd]), pk2(T[tc + 2][nd], T[tc + 3][nd])};
      *reinterpret_cast<uint2*>(&XT0[((size_t)g * LNODES + n0 + nd) * 128 + c0 + tc]) = o;
    }
  } else {
    // -------- single-block CSR build --------
    // 1. zero counts
    for (int i = t; i < LNODES; i += 256) ldeg[i] = 0;
    __syncthreads();
    // 2. count in-degrees (LDS atomics)
    for (int i = 0; i < NEDGE; i += 256) {
      int d = ei[NEDGE + i + t];
      atomicAdd(&ldeg[d], 1);
    }
    __syncthreads();
    // 3. exclusive scan over 2048 counts (256 threads x 8)
    {
      int base = t * 8;
      int loc[8];
      int s = 0;
#pragma unroll
      for (int j = 0; j < 8; ++j) { loc[j] = s; s += ldeg[base + j]; }
      part[t] = s;
      __syncthreads();
      for (int off = 1; off < 256; off <<= 1) {
        int v = (t >= off) ? part[t - off] : 0;
        __syncthreads();
        part[t] += v;
        __syncthreads();
      }
      int excl = (t == 0) ? 0 : part[t - 1];
#pragma unroll
      for (int j = 0; j < 8; ++j) lrp[base + j] = excl + loc[j];
      if (t == 255) lrp[LNODES] = part[255];
    }
    // 4. dis/selfn (reads ldeg; improved=True self loop weight 2)
    for (int i = t; i < LNODES; i += 256) {
      float di = rsqrtf((float)ldeg[i] + 2.0f);
      ldis[i] = di;
      selfn_g[i] = 2.0f * di * di;
    }
    __syncthreads();  // ldeg reads done; lrp/ldis visible to all threads
    // write rp to global (consumed by agg)
    for (int i = t; i <= LNODES; i += 256) rp_g[i] = lrp[i];
    // 5. reuse ldeg as fill cursor
    for (int i = t; i < LNODES; i += 256) ldeg[i] = 0;
    __syncthreads();
    // 6. fill CSR (col, wn)
    for (int i = 0; i < NEDGE; i += 256) {
      int e = i + t;
      int s2 = ei[e], d = ei[NEDGE + e];
      int pos = lrp[d] + atomicAdd(&ldeg[d], 1);
      col[pos] = s2;
      wn[pos] = ldis[s2] * ldis[d];
    }
  }
}

// ---------------- coef reduction helper: shards -> LDS k1/k2/cc ----------------
// st layout per layer: sum1[8][256] | sq1 | sum2 | sq2 (floats, 8192 total)
__device__ __forceinline__ void coef_ld(const float* __restrict__ st,
                                        const float* __restrict__ ga,
                                        const float* __restrict__ be,
                                        const float* __restrict__ gs,
                                        const float* __restrict__ bes,
                                        float* lk1, float* lk2, float* lcc, int t) {
  float sA = 0.f, qA = 0.f, sB = 0.f, qB = 0.f;
#pragma unroll
  for (int x = 0; x < 8; ++x) {
    sA += st[x * NCOUT + t];
    qA += st[2048 + x * NCOUT + t];
    sB += st[4096 + x * NCOUT + t];
    qB += st[6144 + x * NCOUT + t];
  }
  const float c1 = (float)(GBIG * LNODES), c2 = (float)(GSM * LNODES);
  float mA = sA / c1;
  float vA = qA / c1 - mA * mA;
  float kA = ga[t] * rsqrtf(vA + BN_EPS);
  float mB = sB / c2;
  float vB = qB / c2 - mB * mB;
  float kB = gs[t] * rsqrtf(vB + BN_EPS);
  lk1[t] = kA;
  lk2[t] = kB;
  lcc[t] = be[t] - kA * mA + bes[t] - kB * mB;
}

// ---------------- full-K-B MFMA GEMM, 64x256 tile, PIPELINED W-tile staging ----------------
// B tile [64][Cin] staged ONCE into swizzled LDS (fused BN+ReLU(+pool) during staging;
// MODE0 sym: 8-way max-pool of raw XT0 fused into staging).
// W tiles [256 co][32 k]: gl_lds for tile kt+1 issued AFTER tile kt's fragment ds_reads
// (post-WAR-barrier) and BEFORE the MFMA block -> the vmcnt drain at the next top
// barrier overlaps the MFMA phase instead of exposing full L2 latency.
// Epilogue via Csh (coalesced 512B row writes — R13 proved direct stores regress).
template <int MODE>
__global__ __launch_bounds__(256) void gemm3_k(const u16* __restrict__ B1,
                                               const u16* __restrict__ B2,
                                               const float* __restrict__ st,
                                               const float* __restrict__ ga,
                                               const float* __restrict__ be,
                                               const float* __restrict__ gs,
                                               const float* __restrict__ bes,
                                               const u16* __restrict__ WbT,
                                               const u16* __restrict__ WsT,
                                               u16* __restrict__ HW1,
                                               u16* __restrict__ hw2) {
  constexpr int Cin = (MODE == 0) ? 128 : 256;
  constexpr int NT = Cin / 32;
  constexpr int BSH = 64 * Cin;   // B-tile u16 elems
  constexpr int EPI = 64 * 264;   // epilogue Csh u16 elems (16896)
  constexpr int BASE = (BSH > EPI) ? BSH : EPI;
  __shared__ __align__(16) u16 smem[BASE + 8192];  // [0,BASE): Bsh/Csh ; [BASE,+8192): Wsh tile
  __shared__ float lk1[NCOUT], lk2[NCOUT], lcc[NCOUT];
  u16* Wsh = smem + BASE;
  const int z = blockIdx.z;
  const bool sym = z < GSM;
  const int g = sym ? z : z - GSM;
  u16* out = sym ? hw2 : HW1;
  const int n0 = blockIdx.x * 64;
  const int t = threadIdx.x;
  const u16* Wmat = sym ? WsT : WbT;  // K-blocked pre-swizzled layout

  // issue W tile-0 staging EARLY: in flight under the whole B-staging phase
#pragma unroll
  for (int c = 0; c < 4; ++c)
    gl16(Wmat + c * 2048 + t * 8, &Wsh[c * 2048 + t * 8]);

  // staging decomposition: thread -> (row-in-group, channel octet)
  constexpr int OPR = Cin / 8;    // octets per row
  constexpr int RPI = 256 / OPR;  // rows per staging iteration
  constexpr int NIT = 64 / RPI;   // staging iterations
  const int ro = t / OPR;
  const int ch8 = (t % OPR) * 8;

  float K1[8], K2[8], CC[8];
  if constexpr (MODE == 1) {
    coef_ld(st, ga, be, gs, bes, lk1, lk2, lcc, t);
    __syncthreads();
#pragma unroll
    for (int j = 0; j < 8; ++j) { K1[j] = lk1[ch8 + j]; K2[j] = lk2[ch8 + j]; CC[j] = lcc[ch8 + j]; }
  }

  // swizzled B LDS index (u16 units)
#define BIDX(r, c) ((((r) * Cin) + (c)) ^ (((r) & 7) << 3))

  if constexpr (MODE == 0) {
    if (!sym) {
      const u16* src = B1 + ((size_t)g * LNODES + n0) * Cin + ch8;
#pragma unroll
      for (int it = 0; it < NIT; ++it) {
        int row = it * RPI + ro;
        uint4 v = *reinterpret_cast<const uint4*>(&src[(size_t)row * Cin]);
        *reinterpret_cast<uint4*>(&smem[BIDX(row, ch8)]) = v;
      }
    } else {
      // sym MODE 0: fused 8-way max-pool of raw XT0 copies during staging
      const size_t a1b = ((size_t)(g * 8) * LNODES + n0) * Cin + ch8;
      const size_t nstep = (size_t)LNODES * Cin;
      for (int it = 0; it < NIT; ++it) {
        int row = it * RPI + ro;
        uint4 v = *reinterpret_cast<const uint4*>(&B1[a1b + (size_t)row * Cin]);
        float m0 = blo(v.x), m1 = bhi(v.x), m2 = blo(v.y), m3 = bhi(v.y);
        float m4 = blo(v.z), m5 = bhi(v.z), m6 = blo(v.w), m7 = bhi(v.w);
#pragma unroll
        for (int n = 1; n < 8; ++n) {
          uint4 a = *reinterpret_cast<const uint4*>(&B1[a1b + n * nstep + (size_t)row * Cin]);
          m0 = fmaxf(m0, blo(a.x)); m1 = fmaxf(m1, bhi(a.x));
          m2 = fmaxf(m2, blo(a.y)); m3 = fmaxf(m3, bhi(a.y));
          m4 = fmaxf(m4, blo(a.z)); m5 = fmaxf(m5, bhi(a.z));
          m6 = fmaxf(m6, blo(a.w)); m7 = fmaxf(m7, bhi(a.w));
        }
        uint4 ov = {pk2(m0, m1), pk2(m2, m3), pk2(m4, m5), pk2(m6, m7)};
        *reinterpret_cast<uint4*>(&smem[BIDX(row, ch8)]) = ov;
      }
    }
  } else if (!sym) {
    const size_t b1o = ((size_t)g * LNODES + n0) * NCOUT + ch8;
    const size_t b2o = ((size_t)(g >> 3) * LNODES + n0) * NCOUT + ch8;
#pragma unroll
    for (int it = 0; it < NIT; ++it) {
      int row = it * RPI + ro;
      uint4 a1 = *reinterpret_cast<const uint4*>(&B1[b1o + (size_t)row * NCOUT]);
      uint4 a2 = *reinterpret_cast<const uint4*>(&B2[b2o + (size_t)row * NCOUT]);
      float o0 = fmaxf(K1[0] * blo(a1.x) + K2[0] * blo(a2.x) + CC[0], 0.f);
      float o1 = fmaxf(K1[1] * bhi(a1.x) + K2[1] * bhi(a2.x) + CC[1], 0.f);
      float o2 = fmaxf(K1[2] * blo(a1.y) + K2[2] * blo(a2.y) + CC[2], 0.f);
      float o3 = fmaxf(K1[3] * bhi(a1.y) + K2[3] * bhi(a2.y) + CC[3], 0.f);
      float o4 = fmaxf(K1[4] * blo(a1.z) + K2[4] * blo(a2.z) + CC[4], 0.f);
      float o5 = fmaxf(K1[5] * bhi(a1.z) + K2[5] * bhi(a2.z) + CC[5], 0.f);
      float o6 = fmaxf(K1[6] * blo(a1.w) + K2[6] * blo(a2.w) + CC[6], 0.f);
      float o7 = fmaxf(K1[7] * bhi(a1.w) + K2[7] * bhi(a2.w) + CC[7], 0.f);
      uint4 ov = {pk2(o0, o1), pk2(o2, o3), pk2(o4, o5), pk2(o6, o7)};
      *reinterpret_cast<uint4*>(&smem[BIDX(row, ch8)]) = ov;
    }
  } else {
    // sym MODE 1: pooled B = max_n relu(k1*a1_n + (k2*a2 + cc))
    const size_t b2o = ((size_t)g * LNODES + n0) * NCOUT + ch8;
    const size_t a1b = ((size_t)(g * 8) * LNODES + n0) * NCOUT + ch8;
    const size_t nstep = (size_t)LNODES * NCOUT;
    for (int it = 0; it < NIT; ++it) {
      int row = it * RPI + ro;
      uint4 a2 = *reinterpret_cast<const uint4*>(&B2[b2o + (size_t)row * NCOUT]);
      float t0 = K2[0] * blo(a2.x) + CC[0], t1 = K2[1] * bhi(a2.x) + CC[1];
      float t2 = K2[2] * blo(a2.y) + CC[2], t3 = K2[3] * bhi(a2.y) + CC[3];
      float t4 = K2[4] * blo(a2.z) + CC[4], t5 = K2[5] * bhi(a2.z) + CC[5];
      float t6 = K2[6] * blo(a2.w) + CC[6], t7 = K2[7] * bhi(a2.w) + CC[7];
      float m0 = 0.f, m1 = 0.f, m2 = 0.f, m3 = 0.f, m4 = 0.f, m5 = 0.f, m6 = 0.f, m7 = 0.f;
#pragma unroll
      for (int n = 0; n < 8; ++n) {
        uint4 a1 = *reinterpret_cast<const uint4*>(&B1[a1b + n * nstep + (size_t)row * NCOUT]);
        m0 = fmaxf(m0, K1[0] * blo(a1.x) + t0); m1 = fmaxf(m1, K1[1] * bhi(a1.x) + t1);
        m2 = fmaxf(m2, K1[2] * blo(a1.y) + t2); m3 = fmaxf(m3, K1[3] * bhi(a1.y) + t3);
        m4 = fmaxf(m4, K1[4] * blo(a1.z) + t4); m5 = fmaxf(m5, K1[5] * bhi(a1.z) + t5);
        m6 = fmaxf(m6, K1[6] * blo(a1.w) + t6); m7 = fmaxf(m7, K1[7] * bhi(a1.w) + t7);
      }
      uint4 ov = {pk2(m0, m1), pk2(m2, m3), pk2(m4, m5), pk2(m6, m7)};
      *reinterpret_cast<uint4*>(&smem[BIDX(row, ch8)]) = ov;
    }
  }

  const int wv = t >> 6;
  const int lane = t & 63;
  const int q = lane >> 4, l = lane & 15;
  f32x4 zero = {0.f, 0.f, 0.f, 0.f};
  f32x4 acc[4][4];
#pragma unroll
  for (int i = 0; i < 4; ++i)
#pragma unroll
    for (int j = 0; j < 4; ++j) acc[i][j] = zero;

#pragma unroll
  for (int kt = 0; kt < NT; ++kt) {
    __syncthreads();  // drains vmcnt: tile kt loads (in flight since last iter's MFMA) done;
                      // kt=0: also commits B-tile staging
    bf16x8 af[4], bx[4];
#pragma unroll
    for (int fi = 0; fi < 4; ++fi) {
      int row = wv * 64 + fi * 16 + l;
      af[fi] = *reinterpret_cast<const bf16x8*>(&Wsh[(row * 32 + q * 8) ^ ((row & 7) << 3)]);
    }
#pragma unroll
    for (int fj = 0; fj < 4; ++fj) {
      int brow = fj * 16 + l;
      bx[fj] = *reinterpret_cast<const bf16x8*>(&smem[BIDX(brow, kt * 32 + q * 8)]);
    }
    __syncthreads();  // WAR: all waves finished reading Wsh
    if (kt + 1 < NT) {
      const u16* ws = Wmat + (size_t)(kt + 1) * 8192;
#pragma unroll
      for (int c = 0; c < 4; ++c)
        gl16(ws + c * 2048 + t * 8, &Wsh[c * 2048 + t * 8]);
    }
#pragma unroll
    for (int fi = 0; fi < 4; ++fi)
#pragma unroll
      for (int fj = 0; fj < 4; ++fj)
        acc[fi][fj] = __builtin_amdgcn_mfma_f32_16x16x32_bf16(af[fi], bx[fj], acc[fi][fj], 0, 0, 0);
  }
#undef BIDX

  __syncthreads();
  u16* Csh = smem;  // [64][264]
#pragma unroll
  for (int fi = 0; fi < 4; ++fi) {
#pragma unroll
    for (int fj = 0; fj < 4; ++fj) {
      int co_l = wv * 64 + fi * 16 + q * 4;
      int nd_l = fj * 16 + l;
      uint2 pkd = {pk2(acc[fi][fj][0], acc[fi][fj][1]),
                   pk2(acc[fi][fj][2], acc[fi][fj][3])};
      *reinterpret_cast<uint2*>(&Csh[nd_l * 264 + co_l]) = pkd;
    }
  }
  __syncthreads();
#pragma unroll
  for (int p = 0; p < 8; ++p) {
    int idx = p * 256 + t;
    int nd = idx >> 5;
    int c8 = (idx & 31) * 8;
    uint4 v = *reinterpret_cast<const uint4*>(&Csh[nd * 264 + c8]);
    *reinterpret_cast<uint4*>(&out[((size_t)g * LNODES + n0 + nd) * NCOUT + c8]) = v;
  }
}

// ---------------- combined aggregation ----------------
// Big path (1024 blocks): HALF-WAVE G-SPLIT — lanes 0-31 handle g0, lanes 32-63
// handle g0+16. Lane = 8 channels (uint4). Sym path (256 blocks): uint2 layout.
// XCD note: bid&7 = g0 low bits aligns graph slabs to XCDs (4MB/XCD = L2 size).
__global__ __launch_bounds__(256) void agg_comb_k(const u16* __restrict__ HW1,
                                                  const u16* __restrict__ hw2,
                                                  const int* __restrict__ col,
                                                  const float* __restrict__ wn,
                                                  const int* __restrict__ rp,
                                                  const float* __restrict__ selfn,
                                                  u16* __restrict__ AGG1,
                                                  u16* __restrict__ agg2,
                                                  float* __restrict__ st) {
  __shared__ float lsum[8][NCOUT], lsq[8][NCOUT];
  const int bid = blockIdx.x;
  const int t = threadIdx.x;
  const int wv = t >> 6;
  float* sumO;
  float* sqO;
  int shard;
  if (bid < 1024) {
    int slot = bid >> 3;
    int chunk = slot & 63;
    int g0 = (bid & 7) + 8 * (slot >> 6);
    const int d0 = chunk * ND;
    const int h = (t >> 5) & 1;   // half-wave: which graph copy
    const int ch = (t & 31) * 8;  // channel octet
    const u16* baseh = HW1 + (size_t)(g0 + 16 * h) * LNODES * NCOUT;
    u16* outh = AGG1 + (size_t)(g0 + 16 * h) * LNODES * NCOUT;
    float s0 = 0.f, s1 = 0.f, s2 = 0.f, s3 = 0.f, s4 = 0.f, s5 = 0.f, s6 = 0.f, s7 = 0.f;
    float q0 = 0.f, q1 = 0.f, q2 = 0.f, q3 = 0.f, q4 = 0.f, q5 = 0.f, q6 = 0.f, q7 = 0.f;
    for (int i = wv; i < ND; i += 4) {
      int d = d0 + i;
      int e0 = rp[d], e1 = rp[d + 1];
      float sw = selfn[d];
      uint4 u = *reinterpret_cast<const uint4*>(&baseh[(size_t)d * NCOUT + ch]);
      float a0 = sw * blo(u.x), a1 = sw * bhi(u.x), a2 = sw * blo(u.y), a3 = sw * bhi(u.y);
      float a4 = sw * blo(u.z), a5 = sw * bhi(u.z), a6 = sw * blo(u.w), a7 = sw * bhi(u.w);
      int e = e0;
      const int e4 = e0 + ((e1 - e0) & ~3);
      for (; e < e4; e += 4) {
        int i0 = col[e + 0], i1 = col[e + 1], i2 = col[e + 2], i3 = col[e + 3];
        float w0 = wn[e + 0], w1 = wn[e + 1], w2 = wn[e + 2], w3 = wn[e + 3];
        uint4 v0 = *reinterpret_cast<const uint4*>(&baseh[(size_t)i0 * NCOUT + ch]);
        uint4 v1 = *reinterpret_cast<const uint4*>(&baseh[(size_t)i1 * NCOUT + ch]);
        uint4 v2 = *reinterpret_cast<const uint4*>(&baseh[(size_t)i2 * NCOUT + ch]);
        uint4 v3 = *reinterpret_cast<const uint4*>(&baseh[(size_t)i3 * NCOUT + ch]);
        a0 += w0 * blo(v0.x); a1 += w0 * bhi(v0.x); a2 += w0 * blo(v0.y); a3 += w0 * bhi(v0.y);
        a4 += w0 * blo(v0.z); a5 += w0 * bhi(v0.z); a6 += w0 * blo(v0.w); a7 += w0 * bhi(v0.w);
        a0 += w1 * blo(v1.x); a1 += w1 * bhi(v1.x); a2 += w1 * blo(v1.y); a3 += w1 * bhi(v1.y);
        a4 += w1 * blo(v1.z); a5 += w1 * bhi(v1.z); a6 += w1 * blo(v1.w); a7 += w1 * bhi(v1.w);
        a0 += w2 * blo(v2.x); a1 += w2 * bhi(v2.x); a2 += w2 * blo(v2.y); a3 += w2 * bhi(v2.y);
        a4 += w2 * blo(v2.z); a5 += w2 * bhi(v2.z); a6 += w2 * blo(v2.w); a7 += w2 * bhi(v2.w);
        a0 += w3 * blo(v3.x); a1 += w3 * bhi(v3.x); a2 += w3 * blo(v3.y); a3 += w3 * bhi(v3.y);
        a4 += w3 * blo(v3.z); a5 += w3 * bhi(v3.z); a6 += w3 * blo(v3.w); a7 += w3 * bhi(v3.w);
      }
      for (; e < e1; ++e) {
        int ci = col[e];
        float w = wn[e];
        uint4 v = *reinterpret_cast<const uint4*>(&baseh[(size_t)ci * NCOUT + ch]);
        a0 += w * blo(v.x); a1 += w * bhi(v.x); a2 += w * blo(v.y); a3 += w * bhi(v.y);
        a4 += w * blo(v.z); a5 += w * bhi(v.z); a6 += w * blo(v.w); a7 += w * bhi(v.w);
      }
      uint4 o = {pk2(a0, a1), pk2(a2, a3), pk2(a4, a5), pk2(a6, a7)};
      *reinterpret_cast<uint4*>(&outh[(size_t)d * NCOUT + ch]) = o;
      s0 += a0; s1 += a1; s2 += a2; s3 += a3; s4 += a4; s5 += a5; s6 += a6; s7 += a7;
      q0 += a0 * a0; q1 += a1 * a1; q2 += a2 * a2; q3 += a3 * a3;
      q4 += a4 * a4; q5 += a5 * a5; q6 += a6 * a6; q7 += a7 * a7;
    }
    int row = wv * 2 + h;
    float4 sa = {s0, s1, s2, s3}, sb = {s4, s5, s6, s7};
    float4 qa = {q0, q1, q2, q3}, qb = {q4, q5, q6, q7};
    *reinterpret_cast<float4*>(&lsum[row][ch]) = sa;
    *reinterpret_cast<float4*>(&lsum[row][ch + 4]) = sb;
    *reinterpret_cast<float4*>(&lsq[row][ch]) = qa;
    *reinterpret_cast<float4*>(&lsq[row][ch + 4]) = qb;
    sumO = st; sqO = st + 2048; shard = (bid & 7) * NCOUT;
  } else {
    int b2 = bid - 1024;
    int g = b2 & (GSM - 1);
    int chunk = b2 >> 2;
    const int d0 = chunk * ND;
    const int lc = (t & 63) * 4;
    const u16* base = hw2 + (size_t)g * LNODES * NCOUT;
    float4 s = {0.f, 0.f, 0.f, 0.f}, qq = {0.f, 0.f, 0.f, 0.f};
    for (int i = wv; i < ND; i += 4) {
      int d = d0 + i;
      int e0 = rp[d], e1 = rp[d + 1];
      float sw = selfn[d];
      uint2 u = *reinterpret_cast<const uint2*>(&base[(size_t)d * NCOUT + lc]);
      float4 a = {sw * blo(u.x), sw * bhi(u.x), sw * blo(u.y), sw * bhi(u.y)};
      int e = e0;
      const int e4 = e0 + ((e1 - e0) & ~3);
      for (; e < e4; e += 4) {
        int i0 = col[e + 0], i1 = col[e + 1], i2 = col[e + 2], i3 = col[e + 3];
        float w0 = wn[e + 0], w1 = wn[e + 1], w2 = wn[e + 2], w3 = wn[e + 3];
        uint2 v0 = *reinterpret_cast<const uint2*>(&base[(size_t)i0 * NCOUT + lc]);
        uint2 v1 = *reinterpret_cast<const uint2*>(&base[(size_t)i1 * NCOUT + lc]);
        uint2 v2 = *reinterpret_cast<const uint2*>(&base[(size_t)i2 * NCOUT + lc]);
        uint2 v3 = *reinterpret_cast<const uint2*>(&base[(size_t)i3 * NCOUT + lc]);
        a.x += w0 * blo(v0.x); a.y += w0 * bhi(v0.x); a.z += w0 * blo(v0.y); a.w += w0 * bhi(v0.y);
        a.x += w1 * blo(v1.x); a.y += w1 * bhi(v1.x); a.z += w1 * blo(v1.y); a.w += w1 * bhi(v1.y);
        a.x += w2 * blo(v2.x); a.y += w2 * bhi(v2.x); a.z += w2 * blo(v2.y); a.w += w2 * bhi(v2.y);
        a.x += w3 * blo(v3.x); a.y += w3 * bhi(v3.x); a.z += w3 * blo(v3.y); a.w += w3 * bhi(v3.y);
      }
      for (; e < e1; ++e) {
        float w = wn[e];
        uint2 v = *reinterpret_cast<const uint2*>(&base[(size_t)col[e] * NCOUT + lc]);
        a.x += w * blo(v.x); a.y += w * bhi(v.x); a.z += w * blo(v.y); a.w += w * bhi(v.y);
      }
      uint2 o = {pk2(a.x, a.y), pk2(a.z, a.w)};
      *reinterpret_cast<uint2*>(&agg2[((size_t)g * LNODES + d) * NCOUT + lc]) = o;
      s.x += a.x; s.y += a.y; s.z += a.z; s.w += a.w;
      qq.x += a.x * a.x; qq.y += a.y * a.y; qq.z += a.z * a.z; qq.w += a.w * a.w;
    }
    *reinterpret_cast<float4*>(&lsum[wv][lc]) = s;
    *reinterpret_cast<float4*>(&lsq[wv][lc]) = qq;
    float4 z4 = {0.f, 0.f, 0.f, 0.f};
    *reinterpret_cast<float4*>(&lsum[wv + 4][lc]) = z4;
    *reinterpret_cast<float4*>(&lsq[wv + 4][lc]) = z4;
    sumO = st + 4096; sqO = st + 6144; shard = (b2 & 7) * NCOUT;
  }
  __syncthreads();
  float ts = 0.f, tq = 0.f;
#pragma unroll
  for (int r = 0; r < 8; ++r) {
    ts += lsum[r][t];
    tq += lsq[r][t];
  }
  atomicAdd(&sumO[shard + t], ts);
  atomicAdd(&sqO[shard + t], tq);
}

// ---------------- layer 2: fuse + transpose to channel-major fp32 d_out ----------------
__global__ __launch_bounds__(256) void fuse_tr_bf_k(const u16* __restrict__ A1,
                                                    const u16* __restrict__ A2,
                                                    const float* __restrict__ st,
                                                    const float* __restrict__ ga,
                                                    const float* __restrict__ be,
                                                    const float* __restrict__ gs,
                                                    const float* __restrict__ bes,
                                                    float* __restrict__ O) {
  __shared__ float T[64][65];  // [node_local][co_local]
  __shared__ float lk1[NCOUT], lk2[NCOUT], lcc[NCOUT];
  const int g = blockIdx.z;
  const int d0 = blockIdx.x * 64;
  const int c0 = blockIdx.y * 64;
  const int b = g >> 3;
  const int t = threadIdx.x;
  coef_ld(st, ga, be, gs, bes, lk1, lk2, lcc, t);
  __syncthreads();
  const int tr = t >> 4;
  const int tc = (t & 15) * 4;
#pragma unroll
  for (int p = 0; p < 4; ++p) {
    int d = d0 + tr + p * 16;
    uint2 a1 = *reinterpret_cast<const uint2*>(&A1[((size_t)g * LNODES + d) * NCOUT + c0 + tc]);
    uint2 a2 = *reinterpret_cast<const uint2*>(&A2[((size_t)b * LNODES + d) * NCOUT + c0 + tc]);
    int cb = c0 + tc;
    T[tr + p * 16][tc + 0] = fmaxf(lk1[cb+0] * blo(a1.x) + lk2[cb+0] * blo(a2.x) + lcc[cb+0], 0.f);
    T[tr + p * 16][tc + 1] = fmaxf(lk1[cb+1] * bhi(a1.x) + lk2[cb+1] * bhi(a2.x) + lcc[cb+1], 0.f);
    T[tr + p * 16][tc + 2] = fmaxf(lk1[cb+2] * blo(a1.y) + lk2[cb+2] * blo(a2.y) + lcc[cb+2], 0.f);
    T[tr + p * 16][tc + 3] = fmaxf(lk1[cb+3] * bhi(a1.y) + lk2[cb+3] * bhi(a2.y) + lcc[cb+3], 0.f);
  }
  __syncthreads();
#pragma unroll
  for (int p = 0; p < 4; ++p) {
    int c = tr + p * 16;
    float4 o = {T[tc + 0][c], T[tc + 1][c], T[tc + 2][c], T[tc + 3][c]};
    *reinterpret_cast<float4*>(&O[((size_t)g * NCOUT + c0 + c) * LNODES + d0 + tc]) = o;
  }
}

// ---------------- launch ----------------

extern "C" void kernel_launch(void* const* d_in, const int* in_sizes, int n_in,
                              void* d_out, int out_size, void* d_ws, size_t ws_size,
                              hipStream_t stream) {
  const float* x_in = (const float*)d_in[0];
  const int* ei = (const int*)d_in[1];
  const float* W[3]   = {(const float*)d_in[2],  (const float*)d_in[4],  (const float*)d_in[6]};
  const float* Wsym[3]= {(const float*)d_in[8],  (const float*)d_in[10], (const float*)d_in[12]};
  const float* ga[3]  = {(const float*)d_in[14], (const float*)d_in[16], (const float*)d_in[18]};
  const float* be[3]  = {(const float*)d_in[15], (const float*)d_in[17], (const float*)d_in[19]};
  const float* gs[3]  = {(const float*)d_in[20], (const float*)d_in[22], (const float*)d_in[24]};
  const float* bes[3] = {(const float*)d_in[21], (const float*)d_in[23], (const float*)d_in[25]};

  const size_t EBIG = (size_t)GBIG * LNODES * NCOUT;  // 16.7M elems
  const size_t ESM = (size_t)GSM * LNODES * NCOUT;
  char* p = (char*)d_ws;
  u16* XT0  = (u16*)p; p += (size_t)GBIG * LNODES * 128 * 2;  // 16 MiB layer-0 input
  u16* AGG1 = (u16*)p; p += EBIG * 2;   // 32 MiB
  u16* agg2 = (u16*)p; p += ESM * 2;    // 4 MiB
  u16* hw2  = (u16*)p; p += ESM * 2;    // 4 MiB
  u16* WbT[3], *WsT[3];
  for (int i = 0; i < 3; ++i) { WbT[i] = (u16*)p; p += NCOUT * NCOUT * 2; }
  for (int i = 0; i < 3; ++i) { WsT[i] = (u16*)p; p += NCOUT * NCOUT * 2; }
  int*   rp   = (int*)p;   p += 2064 * 4;
  float* selfn= (float*)p; p += LNODES * 4;
  int*   col  = (int*)p;   p += (NEDGE + 8) * 4;
  float* wn   = (float*)p; p += (NEDGE + 8) * 4;
  float* stats= (float*)p; p += 3 * 4 * 2048 * 4; // [3 layers][sum1|sq1|sum2|sq2][8][256]

  u16* HW1 = (u16*)d_out;  // big GEMM out in d_out (dead by fuse_tr time)
  float* stL[3] = {stats, stats + 8192, stats + 16384};

  // ---- setup: stats zero + ONE merged setup kernel (weights/transpose/CSR) ----
  hipMemsetAsync(stats, 0, 3 * 4 * 2048 * 4, stream);
  WCvt wc;
  for (int i = 0; i < 3; ++i) {
    wc.src[i] = W[i];     wc.dst[i] = WbT[i];     wc.ci[i] = (i == 0) ? 128 : 256;
    wc.src[3 + i] = Wsym[i]; wc.dst[3 + i] = WsT[i]; wc.ci[3 + i] = (i == 0) ? 128 : 256;
  }
  setup1_k<<<2145, 256, 0, stream>>>(ei, wc, x_in, XT0, rp, selfn, col, wn);

  dim3 ggrid(LNODES / 64, 1, GBIG + GSM);
  // layer 0 (sym pool fused into staging)
  gemm3_k<0><<<ggrid, 256, 0, stream>>>(XT0, nullptr, nullptr, nullptr, nullptr, nullptr,
                                        nullptr, WbT[0], WsT[0], HW1, hw2);
  agg_comb_k<<<1280, 256, 0, stream>>>(HW1, hw2, col, wn, rp, selfn, AGG1, agg2, stL[0]);
  // layer 1 (BN+ReLU fuse of layer-0 agg happens inside B-staging)
  gemm3_k<1><<<ggrid, 256, 0, stream>>>(AGG1, agg2, stL[0], ga[0], be[0], gs[0], bes[0],
                                        WbT[1], WsT[1], HW1, hw2);
  agg_comb_k<<<1280, 256, 0, stream>>>(HW1, hw2, col, wn, rp, selfn, AGG1, agg2, stL[1]);
  // layer 2
  gemm3_k<1><<<ggrid, 256, 0, stream>>>(AGG1, agg2, stL[1], ga[1], be[1], gs[1], bes[1],
                                        WbT[2], WsT[2], HW1, hw2);
  agg_comb_k<<<1280, 256, 0, stream>>>(HW1, hw2, col, wn, rp, selfn, AGG1, agg2, stL[2]);
  fuse_tr_bf_k<<<dim3(LNODES / 64, NCOUT / 64, GBIG), 256, 0, stream>>>(
      AGG1, agg2, stL[2], ga[2], be[2], gs[2], bes[2], (float*)d_out);
}

// Round 19
// 330.941 us; speedup vs baseline: 1.1129x; 1.1129x over previous
//
#include <hip/hip_runtime.h>
#include <math.h>

#define LNODES 2048
#define NEDGE 16384
#define GBIG 32
#define GSM 4
#define NCOUT 256
#define BN_EPS 1e-5f
#define ND 32  // dst nodes per agg block

typedef unsigned short u16;
typedef __attribute__((ext_vector_type(8))) short bf16x8;
typedef __attribute__((ext_vector_type(4))) float f32x4;

__device__ __forceinline__ unsigned pk2(float a, float b) {  // a->lo, b->hi
  unsigned ua = __float_as_uint(a); ua += 0x7fffu + ((ua >> 16) & 1u);
  unsigned ub = __float_as_uint(b); ub += 0x7fffu + ((ub >> 16) & 1u);
  return (ua >> 16) | (ub & 0xffff0000u);
}
__device__ __forceinline__ float blo(unsigned u) { return __uint_as_float(u << 16); }
__device__ __forceinline__ float bhi(unsigned u) { return __uint_as_float(u & 0xffff0000u); }

// async global->LDS, 16B per lane. LDS dest must be wave-uniform base + lane*16.
__device__ __forceinline__ void gl16(const u16* g, u16* l) {
  __builtin_amdgcn_global_load_lds(
      (const __attribute__((address_space(1))) void*)g,
      (__attribute__((address_space(3))) void*)l, 16, 0, 0);
}

// ================= merged setup kernels (3 dispatches; NOTE: do NOT merge the
// CSR build into setup1 — R18 proved the CSR branch's 25.6KB LDS gets statically
// added to ALL blocks' footprint, collapsing streaming occupancy) =================

struct WCvt {
  const float* src[6];
  u16* dst[6];
  int ci[6];
};

// setup1: count_deg (64 blocks) | cvtw K-blocked pre-swizzled (96) | trans (2048)
__global__ __launch_bounds__(256) void setup1_k(const int* __restrict__ ei,
                                                float* __restrict__ deg,
                                                int* __restrict__ cnt,
                                                WCvt wp,
                                                const float* __restrict__ x_in,
                                                u16* __restrict__ XT0) {
  __shared__ float T[64][65];
  const int bid = blockIdx.x;
  const int t = threadIdx.x;
  if (bid < 64) {
    int e = bid * 256 + t;
    int d = ei[NEDGE + e];
    atomicAdd(&deg[d], 1.0f);
    atomicAdd(&cnt[d], 1);
  } else if (bid < 160) {
    // weights: W [Ci][256] f32 -> WTb[kt][ (co*32+kk) ^ ((co&7)<<3) ] bf16
    const int w = bid - 64;
    const int bz = w >> 4;
    const int Ci = wp.ci[bz];
    const int ci0 = ((w >> 2) & 3) * 64;
    if (ci0 >= Ci) return;
    const float* W = wp.src[bz];
    u16* WT = wp.dst[bz];
    const int co0 = (w & 3) * 64;
    const int tr = t >> 4;
    const int tc = (t & 15) * 4;
#pragma unroll
    for (int p = 0; p < 4; ++p) {
      int ci = ci0 + tr + p * 16;
      float4 v = *reinterpret_cast<const float4*>(&W[(size_t)ci * NCOUT + co0 + tc]);
      T[tr + p * 16][tc + 0] = v.x; T[tr + p * 16][tc + 1] = v.y;
      T[tr + p * 16][tc + 2] = v.z; T[tr + p * 16][tc + 3] = v.w;
    }
    __syncthreads();
    const int ci = ci0 + tc;        // multiple of 4
    const int kt = ci >> 5;
    const int kk = ci & 31;         // 4-aligned -> uint2 stays aligned after XOR
#pragma unroll
    for (int p = 0; p < 4; ++p) {
      int co = co0 + tr + p * 16;
      uint2 o = {pk2(T[tc + 0][co - co0], T[tc + 1][co - co0]),
                 pk2(T[tc + 2][co - co0], T[tc + 3][co - co0])};
      size_t idx = (size_t)kt * 8192 + (unsigned)((co * 32 + kk) ^ ((co & 7) << 3));
      *reinterpret_cast<uint2*>(&WT[idx]) = o;
    }
  } else {
    // x [G][128][L] f32 -> XT [G][L][128] bf16
    const int w = bid - 160;
    const int g = w >> 6;
    const int n0 = (w & 31) * 64;
    const int c0 = ((w >> 5) & 1) * 64;
    const int tr = t >> 4;
    const int tc = (t & 15) * 4;
#pragma unroll
    for (int p = 0; p < 4; ++p) {
      int ci = c0 + tr + p * 16;
      float4 v = *reinterpret_cast<const float4*>(&x_in[((size_t)g * 128 + ci) * LNODES + n0 + tc]);
      T[tr + p * 16][tc + 0] = v.x; T[tr + p * 16][tc + 1] = v.y;
      T[tr + p * 16][tc + 2] = v.z; T[tr + p * 16][tc + 3] = v.w;
    }
    __syncthreads();
#pragma unroll
    for (int p = 0; p < 4; ++p) {
      int nd = tr + p * 16;
      uint2 o = {pk2(T[tc + 0][nd], T[tc + 1][nd]), pk2(T[tc + 2][nd], T[tc + 3][nd])};
      *reinterpret_cast<uint2*>(&XT0[((size_t)g * LNODES + n0 + nd) * 128 + c0 + tc]) = o;
    }
  }
}

// setup2: dis (blocks 0-7) | scan (block 8)
__global__ __launch_bounds__(256) void setup2_k(const float* __restrict__ deg,
                                                float* __restrict__ dis,
                                                float* __restrict__ selfn,
                                                const int* __restrict__ cnt,
                                                int* __restrict__ rp) {
  __shared__ int part[256];
  const int t = threadIdx.x;
  if (blockIdx.x == 8) {
    int base = t * 8;
    int loc[8];
    int s = 0;
#pragma unroll
    for (int j = 0; j < 8; ++j) { loc[j] = s; s += cnt[base + j]; }
    part[t] = s;
    __syncthreads();
    for (int off = 1; off < 256; off <<= 1) {
      int v = (t >= off) ? part[t - off] : 0;
      __syncthreads();
      part[t] += v;
      __syncthreads();
    }
    int excl = (t == 0) ? 0 : part[t - 1];
#pragma unroll
    for (int j = 0; j < 8; ++j) rp[base + j] = excl + loc[j];
    if (t == 255) rp[LNODES] = part[255];
  } else {
    int i = blockIdx.x * 256 + t;
    float di = rsqrtf(deg[i] + 2.0f);  // improved=True self loop weight 2
    dis[i] = di;
    selfn[i] = 2.0f * di * di;
  }
}

// setup3: CSR fill only (pool is fused into gemm0's sym staging)
__global__ __launch_bounds__(256) void setup3_k(const int* __restrict__ ei,
                                                const int* __restrict__ rp,
                                                int* __restrict__ fillc,
                                                const float* __restrict__ dis,
                                                int* __restrict__ col,
                                                float* __restrict__ wn) {
  int e = blockIdx.x * 256 + threadIdx.x;
  int s = ei[e], d = ei[NEDGE + e];
  int pos = rp[d] + atomicAdd(&fillc[d], 1);
  col[pos] = s;
  wn[pos] = dis[s] * dis[d];
}

// ---------------- coef reduction helper: shards -> LDS k1/k2/cc ----------------
// st layout per layer: sum1[8][256] | sq1 | sum2 | sq2 (floats, 8192 total)
__device__ __forceinline__ void coef_ld(const float* __restrict__ st,
                                        const float* __restrict__ ga,
                                        const float* __restrict__ be,
                                        const float* __restrict__ gs,
                                        const float* __restrict__ bes,
                                        float* lk1, float* lk2, float* lcc, int t) {
  float sA = 0.f, qA = 0.f, sB = 0.f, qB = 0.f;
#pragma unroll
  for (int x = 0; x < 8; ++x) {
    sA += st[x * NCOUT + t];
    qA += st[2048 + x * NCOUT + t];
    sB += st[4096 + x * NCOUT + t];
    qB += st[6144 + x * NCOUT + t];
  }
  const float c1 = (float)(GBIG * LNODES), c2 = (float)(GSM * LNODES);
  float mA = sA / c1;
  float vA = qA / c1 - mA * mA;
  float kA = ga[t] * rsqrtf(vA + BN_EPS);
  float mB = sB / c2;
  float vB = qB / c2 - mB * mB;
  float kB = gs[t] * rsqrtf(vB + BN_EPS);
  lk1[t] = kA;
  lk2[t] = kB;
  lcc[t] = be[t] - kA * mA + bes[t] - kB * mB;
}

// ---------------- full-K-B MFMA GEMM, 64x256 tile, PIPELINED W-tile staging ----------------
// B tile [64][Cin] staged ONCE into swizzled LDS (fused BN+ReLU(+pool) during staging;
// MODE0 sym: 8-way max-pool of raw XT0 fused into staging).
// W tiles [256 co][32 k]: gl_lds for tile kt+1 issued AFTER tile kt's fragment ds_reads
// (post-WAR-barrier) and BEFORE the MFMA block -> the vmcnt drain at the next top
// barrier overlaps the MFMA phase instead of exposing full L2 latency.
// Epilogue via Csh (coalesced 512B row writes — R13 proved direct stores regress).
template <int MODE>
__global__ __launch_bounds__(256) void gemm3_k(const u16* __restrict__ B1,
                                               const u16* __restrict__ B2,
                                               const float* __restrict__ st,
                                               const float* __restrict__ ga,
                                               const float* __restrict__ be,
                                               const float* __restrict__ gs,
                                               const float* __restrict__ bes,
                                               const u16* __restrict__ WbT,
                                               const u16* __restrict__ WsT,
                                               u16* __restrict__ HW1,
                                               u16* __restrict__ hw2) {
  constexpr int Cin = (MODE == 0) ? 128 : 256;
  constexpr int NT = Cin / 32;
  constexpr int BSH = 64 * Cin;   // B-tile u16 elems
  constexpr int EPI = 64 * 264;   // epilogue Csh u16 elems (16896)
  constexpr int BASE = (BSH > EPI) ? BSH : EPI;
  __shared__ __align__(16) u16 smem[BASE + 8192];  // [0,BASE): Bsh/Csh ; [BASE,+8192): Wsh tile
  __shared__ float lk1[NCOUT], lk2[NCOUT], lcc[NCOUT];
  u16* Wsh = smem + BASE;
  const int z = blockIdx.z;
  const bool sym = z < GSM;
  const int g = sym ? z : z - GSM;
  u16* out = sym ? hw2 : HW1;
  const int n0 = blockIdx.x * 64;
  const int t = threadIdx.x;
  const u16* Wmat = sym ? WsT : WbT;  // K-blocked pre-swizzled layout

  // issue W tile-0 staging EARLY: in flight under the whole B-staging phase
#pragma unroll
  for (int c = 0; c < 4; ++c)
    gl16(Wmat + c * 2048 + t * 8, &Wsh[c * 2048 + t * 8]);

  // staging decomposition: thread -> (row-in-group, channel octet)
  constexpr int OPR = Cin / 8;    // octets per row
  constexpr int RPI = 256 / OPR;  // rows per staging iteration
  constexpr int NIT = 64 / RPI;   // staging iterations
  const int ro = t / OPR;
  const int ch8 = (t % OPR) * 8;

  float K1[8], K2[8], CC[8];
  if constexpr (MODE == 1) {
    coef_ld(st, ga, be, gs, bes, lk1, lk2, lcc, t);
    __syncthreads();
#pragma unroll
    for (int j = 0; j < 8; ++j) { K1[j] = lk1[ch8 + j]; K2[j] = lk2[ch8 + j]; CC[j] = lcc[ch8 + j]; }
  }

  // swizzled B LDS index (u16 units)
#define BIDX(r, c) ((((r) * Cin) + (c)) ^ (((r) & 7) << 3))

  if constexpr (MODE == 0) {
    if (!sym) {
      const u16* src = B1 + ((size_t)g * LNODES + n0) * Cin + ch8;
#pragma unroll
      for (int it = 0; it < NIT; ++it) {
        int row = it * RPI + ro;
        uint4 v = *reinterpret_cast<const uint4*>(&src[(size_t)row * Cin]);
        *reinterpret_cast<uint4*>(&smem[BIDX(row, ch8)]) = v;
      }
    } else {
      // sym MODE 0: fused 8-way max-pool of raw XT0 copies during staging
      const size_t a1b = ((size_t)(g * 8) * LNODES + n0) * Cin + ch8;
      const size_t nstep = (size_t)LNODES * Cin;
      for (int it = 0; it < NIT; ++it) {
        int row = it * RPI + ro;
        uint4 v = *reinterpret_cast<const uint4*>(&B1[a1b + (size_t)row * Cin]);
        float m0 = blo(v.x), m1 = bhi(v.x), m2 = blo(v.y), m3 = bhi(v.y);
        float m4 = blo(v.z), m5 = bhi(v.z), m6 = blo(v.w), m7 = bhi(v.w);
#pragma unroll
        for (int n = 1; n < 8; ++n) {
          uint4 a = *reinterpret_cast<const uint4*>(&B1[a1b + n * nstep + (size_t)row * Cin]);
          m0 = fmaxf(m0, blo(a.x)); m1 = fmaxf(m1, bhi(a.x));
          m2 = fmaxf(m2, blo(a.y)); m3 = fmaxf(m3, bhi(a.y));
          m4 = fmaxf(m4, blo(a.z)); m5 = fmaxf(m5, bhi(a.z));
          m6 = fmaxf(m6, blo(a.w)); m7 = fmaxf(m7, bhi(a.w));
        }
        uint4 ov = {pk2(m0, m1), pk2(m2, m3), pk2(m4, m5), pk2(m6, m7)};
        *reinterpret_cast<uint4*>(&smem[BIDX(row, ch8)]) = ov;
      }
    }
  } else if (!sym) {
    const size_t b1o = ((size_t)g * LNODES + n0) * NCOUT + ch8;
    const size_t b2o = ((size_t)(g >> 3) * LNODES + n0) * NCOUT + ch8;
#pragma unroll
    for (int it = 0; it < NIT; ++it) {
      int row = it * RPI + ro;
      uint4 a1 = *reinterpret_cast<const uint4*>(&B1[b1o + (size_t)row * NCOUT]);
      uint4 a2 = *reinterpret_cast<const uint4*>(&B2[b2o + (size_t)row * NCOUT]);
      float o0 = fmaxf(K1[0] * blo(a1.x) + K2[0] * blo(a2.x) + CC[0], 0.f);
      float o1 = fmaxf(K1[1] * bhi(a1.x) + K2[1] * bhi(a2.x) + CC[1], 0.f);
      float o2 = fmaxf(K1[2] * blo(a1.y) + K2[2] * blo(a2.y) + CC[2], 0.f);
      float o3 = fmaxf(K1[3] * bhi(a1.y) + K2[3] * bhi(a2.y) + CC[3], 0.f);
      float o4 = fmaxf(K1[4] * blo(a1.z) + K2[4] * blo(a2.z) + CC[4], 0.f);
      float o5 = fmaxf(K1[5] * bhi(a1.z) + K2[5] * bhi(a2.z) + CC[5], 0.f);
      float o6 = fmaxf(K1[6] * blo(a1.w) + K2[6] * blo(a2.w) + CC[6], 0.f);
      float o7 = fmaxf(K1[7] * bhi(a1.w) + K2[7] * bhi(a2.w) + CC[7], 0.f);
      uint4 ov = {pk2(o0, o1), pk2(o2, o3), pk2(o4, o5), pk2(o6, o7)};
      *reinterpret_cast<uint4*>(&smem[BIDX(row, ch8)]) = ov;
    }
  } else {
    // sym MODE 1: pooled B = max_n relu(k1*a1_n + (k2*a2 + cc))
    const size_t b2o = ((size_t)g * LNODES + n0) * NCOUT + ch8;
    const size_t a1b = ((size_t)(g * 8) * LNODES + n0) * NCOUT + ch8;
    const size_t nstep = (size_t)LNODES * NCOUT;
    for (int it = 0; it < NIT; ++it) {
      int row = it * RPI + ro;
      uint4 a2 = *reinterpret_cast<const uint4*>(&B2[b2o + (size_t)row * NCOUT]);
      float t0 = K2[0] * blo(a2.x) + CC[0], t1 = K2[1] * bhi(a2.x) + CC[1];
      float t2 = K2[2] * blo(a2.y) + CC[2], t3 = K2[3] * bhi(a2.y) + CC[3];
      float t4 = K2[4] * blo(a2.z) + CC[4], t5 = K2[5] * bhi(a2.z) + CC[5];
      float t6 = K2[6] * blo(a2.w) + CC[6], t7 = K2[7] * bhi(a2.w) + CC[7];
      float m0 = 0.f, m1 = 0.f, m2 = 0.f, m3 = 0.f, m4 = 0.f, m5 = 0.f, m6 = 0.f, m7 = 0.f;
#pragma unroll
      for (int n = 0; n < 8; ++n) {
        uint4 a1 = *reinterpret_cast<const uint4*>(&B1[a1b + n * nstep + (size_t)row * NCOUT]);
        m0 = fmaxf(m0, K1[0] * blo(a1.x) + t0); m1 = fmaxf(m1, K1[1] * bhi(a1.x) + t1);
        m2 = fmaxf(m2, K1[2] * blo(a1.y) + t2); m3 = fmaxf(m3, K1[3] * bhi(a1.y) + t3);
        m4 = fmaxf(m4, K1[4] * blo(a1.z) + t4); m5 = fmaxf(m5, K1[5] * bhi(a1.z) + t5);
        m6 = fmaxf(m6, K1[6] * blo(a1.w) + t6); m7 = fmaxf(m7, K1[7] * bhi(a1.w) + t7);
      }
      uint4 ov = {pk2(m0, m1), pk2(m2, m3), pk2(m4, m5), pk2(m6, m7)};
      *reinterpret_cast<uint4*>(&smem[BIDX(row, ch8)]) = ov;
    }
  }

  const int wv = t >> 6;
  const int lane = t & 63;
  const int q = lane >> 4, l = lane & 15;
  f32x4 zero = {0.f, 0.f, 0.f, 0.f};
  f32x4 acc[4][4];
#pragma unroll
  for (int i = 0; i < 4; ++i)
#pragma unroll
    for (int j = 0; j < 4; ++j) acc[i][j] = zero;

#pragma unroll
  for (int kt = 0; kt < NT; ++kt) {
    __syncthreads();  // drains vmcnt: tile kt loads (in flight since last iter's MFMA) done;
                      // kt=0: also commits B-tile staging
    bf16x8 af[4], bx[4];
#pragma unroll
    for (int fi = 0; fi < 4; ++fi) {
      int row = wv * 64 + fi * 16 + l;
      af[fi] = *reinterpret_cast<const bf16x8*>(&Wsh[(row * 32 + q * 8) ^ ((row & 7) << 3)]);
    }
#pragma unroll
    for (int fj = 0; fj < 4; ++fj) {
      int brow = fj * 16 + l;
      bx[fj] = *reinterpret_cast<const bf16x8*>(&smem[BIDX(brow, kt * 32 + q * 8)]);
    }
    __syncthreads();  // WAR: all waves finished reading Wsh
    if (kt + 1 < NT) {
      const u16* ws = Wmat + (size_t)(kt + 1) * 8192;
#pragma unroll
      for (int c = 0; c < 4; ++c)
        gl16(ws + c * 2048 + t * 8, &Wsh[c * 2048 + t * 8]);
    }
#pragma unroll
    for (int fi = 0; fi < 4; ++fi)
#pragma unroll
      for (int fj = 0; fj < 4; ++fj)
        acc[fi][fj] = __builtin_amdgcn_mfma_f32_16x16x32_bf16(af[fi], bx[fj], acc[fi][fj], 0, 0, 0);
  }
#undef BIDX

  __syncthreads();
  u16* Csh = smem;  // [64][264]
#pragma unroll
  for (int fi = 0; fi < 4; ++fi) {
#pragma unroll
    for (int fj = 0; fj < 4; ++fj) {
      int co_l = wv * 64 + fi * 16 + q * 4;
      int nd_l = fj * 16 + l;
      uint2 pkd = {pk2(acc[fi][fj][0], acc[fi][fj][1]),
                   pk2(acc[fi][fj][2], acc[fi][fj][3])};
      *reinterpret_cast<uint2*>(&Csh[nd_l * 264 + co_l]) = pkd;
    }
  }
  __syncthreads();
#pragma unroll
  for (int p = 0; p < 8; ++p) {
    int idx = p * 256 + t;
    int nd = idx >> 5;
    int c8 = (idx & 31) * 8;
    uint4 v = *reinterpret_cast<const uint4*>(&Csh[nd * 264 + c8]);
    *reinterpret_cast<uint4*>(&out[((size_t)g * LNODES + n0 + nd) * NCOUT + c8]) = v;
  }
}

// ---------------- combined aggregation ----------------
// Big path (1024 blocks): HALF-WAVE G-SPLIT — lanes 0-31 handle g0, lanes 32-63
// handle g0+16. Lane = 8 channels (uint4). Sym path (256 blocks): uint2 layout.
// XCD note: bid&7 = g0 low bits aligns graph slabs to XCDs (4MB/XCD = L2 size).
__global__ __launch_bounds__(256) void agg_comb_k(const u16* __restrict__ HW1,
                                                  const u16* __restrict__ hw2,
                                                  const int* __restrict__ col,
                                                  const float* __restrict__ wn,
                                                  const int* __restrict__ rp,
                                                  const float* __restrict__ selfn,
                                                  u16* __restrict__ AGG1,
                                                  u16* __restrict__ agg2,
                                                  float* __restrict__ st) {
  __shared__ float lsum[8][NCOUT], lsq[8][NCOUT];
  const int bid = blockIdx.x;
  const int t = threadIdx.x;
  const int wv = t >> 6;
  float* sumO;
  float* sqO;
  int shard;
  if (bid < 1024) {
    int slot = bid >> 3;
    int chunk = slot & 63;
    int g0 = (bid & 7) + 8 * (slot >> 6);
    const int d0 = chunk * ND;
    const int h = (t >> 5) & 1;   // half-wave: which graph copy
    const int ch = (t & 31) * 8;  // channel octet
    const u16* baseh = HW1 + (size_t)(g0 + 16 * h) * LNODES * NCOUT;
    u16* outh = AGG1 + (size_t)(g0 + 16 * h) * LNODES * NCOUT;
    float s0 = 0.f, s1 = 0.f, s2 = 0.f, s3 = 0.f, s4 = 0.f, s5 = 0.f, s6 = 0.f, s7 = 0.f;
    float q0 = 0.f, q1 = 0.f, q2 = 0.f, q3 = 0.f, q4 = 0.f, q5 = 0.f, q6 = 0.f, q7 = 0.f;
    for (int i = wv; i < ND; i += 4) {
      int d = d0 + i;
      int e0 = rp[d], e1 = rp[d + 1];
      float sw = selfn[d];
      uint4 u = *reinterpret_cast<const uint4*>(&baseh[(size_t)d * NCOUT + ch]);
      float a0 = sw * blo(u.x), a1 = sw * bhi(u.x), a2 = sw * blo(u.y), a3 = sw * bhi(u.y);
      float a4 = sw * blo(u.z), a5 = sw * bhi(u.z), a6 = sw * blo(u.w), a7 = sw * bhi(u.w);
      int e = e0;
      const int e4 = e0 + ((e1 - e0) & ~3);
      for (; e < e4; e += 4) {
        int i0 = col[e + 0], i1 = col[e + 1], i2 = col[e + 2], i3 = col[e + 3];
        float w0 = wn[e + 0], w1 = wn[e + 1], w2 = wn[e + 2], w3 = wn[e + 3];
        uint4 v0 = *reinterpret_cast<const uint4*>(&baseh[(size_t)i0 * NCOUT + ch]);
        uint4 v1 = *reinterpret_cast<const uint4*>(&baseh[(size_t)i1 * NCOUT + ch]);
        uint4 v2 = *reinterpret_cast<const uint4*>(&baseh[(size_t)i2 * NCOUT + ch]);
        uint4 v3 = *reinterpret_cast<const uint4*>(&baseh[(size_t)i3 * NCOUT + ch]);
        a0 += w0 * blo(v0.x); a1 += w0 * bhi(v0.x); a2 += w0 * blo(v0.y); a3 += w0 * bhi(v0.y);
        a4 += w0 * blo(v0.z); a5 += w0 * bhi(v0.z); a6 += w0 * blo(v0.w); a7 += w0 * bhi(v0.w);
        a0 += w1 * blo(v1.x); a1 += w1 * bhi(v1.x); a2 += w1 * blo(v1.y); a3 += w1 * bhi(v1.y);
        a4 += w1 * blo(v1.z); a5 += w1 * bhi(v1.z); a6 += w1 * blo(v1.w); a7 += w1 * bhi(v1.w);
        a0 += w2 * blo(v2.x); a1 += w2 * bhi(v2.x); a2 += w2 * blo(v2.y); a3 += w2 * bhi(v2.y);
        a4 += w2 * blo(v2.z); a5 += w2 * bhi(v2.z); a6 += w2 * blo(v2.w); a7 += w2 * bhi(v2.w);
        a0 += w3 * blo(v3.x); a1 += w3 * bhi(v3.x); a2 += w3 * blo(v3.y); a3 += w3 * bhi(v3.y);
        a4 += w3 * blo(v3.z); a5 += w3 * bhi(v3.z); a6 += w3 * blo(v3.w); a7 += w3 * bhi(v3.w);
      }
      for (; e < e1; ++e) {
        int ci = col[e];
        float w = wn[e];
        uint4 v = *reinterpret_cast<const uint4*>(&baseh[(size_t)ci * NCOUT + ch]);
        a0 += w * blo(v.x); a1 += w * bhi(v.x); a2 += w * blo(v.y); a3 += w * bhi(v.y);
        a4 += w * blo(v.z); a5 += w * bhi(v.z); a6 += w * blo(v.w); a7 += w * bhi(v.w);
      }
      uint4 o = {pk2(a0, a1), pk2(a2, a3), pk2(a4, a5), pk2(a6, a7)};
      *reinterpret_cast<uint4*>(&outh[(size_t)d * NCOUT + ch]) = o;
      s0 += a0; s1 += a1; s2 += a2; s3 += a3; s4 += a4; s5 += a5; s6 += a6; s7 += a7;
      q0 += a0 * a0; q1 += a1 * a1; q2 += a2 * a2; q3 += a3 * a3;
      q4 += a4 * a4; q5 += a5 * a5; q6 += a6 * a6; q7 += a7 * a7;
    }
    int row = wv * 2 + h;
    float4 sa = {s0, s1, s2, s3}, sb = {s4, s5, s6, s7};
    float4 qa = {q0, q1, q2, q3}, qb = {q4, q5, q6, q7};
    *reinterpret_cast<float4*>(&lsum[row][ch]) = sa;
    *reinterpret_cast<float4*>(&lsum[row][ch + 4]) = sb;
    *reinterpret_cast<float4*>(&lsq[row][ch]) = qa;
    *reinterpret_cast<float4*>(&lsq[row][ch + 4]) = qb;
    sumO = st; sqO = st + 2048; shard = (bid & 7) * NCOUT;
  } else {
    int b2 = bid - 1024;
    int g = b2 & (GSM - 1);
    int chunk = b2 >> 2;
    const int d0 = chunk * ND;
    const int lc = (t & 63) * 4;
    const u16* base = hw2 + (size_t)g * LNODES * NCOUT;
    float4 s = {0.f, 0.f, 0.f, 0.f}, qq = {0.f, 0.f, 0.f, 0.f};
    for (int i = wv; i < ND; i += 4) {
      int d = d0 + i;
      int e0 = rp[d], e1 = rp[d + 1];
      float sw = selfn[d];
      uint2 u = *reinterpret_cast<const uint2*>(&base[(size_t)d * NCOUT + lc]);
      float4 a = {sw * blo(u.x), sw * bhi(u.x), sw * blo(u.y), sw * bhi(u.y)};
      int e = e0;
      const int e4 = e0 + ((e1 - e0) & ~3);
      for (; e < e4; e += 4) {
        int i0 = col[e + 0], i1 = col[e + 1], i2 = col[e + 2], i3 = col[e + 3];
        float w0 = wn[e + 0], w1 = wn[e + 1], w2 = wn[e + 2], w3 = wn[e + 3];
        uint2 v0 = *reinterpret_cast<const uint2*>(&base[(size_t)i0 * NCOUT + lc]);
        uint2 v1 = *reinterpret_cast<const uint2*>(&base[(size_t)i1 * NCOUT + lc]);
        uint2 v2 = *reinterpret_cast<const uint2*>(&base[(size_t)i2 * NCOUT + lc]);
        uint2 v3 = *reinterpret_cast<const uint2*>(&base[(size_t)i3 * NCOUT + lc]);
        a.x += w0 * blo(v0.x); a.y += w0 * bhi(v0.x); a.z += w0 * blo(v0.y); a.w += w0 * bhi(v0.y);
        a.x += w1 * blo(v1.x); a.y += w1 * bhi(v1.x); a.z += w1 * blo(v1.y); a.w += w1 * bhi(v1.y);
        a.x += w2 * blo(v2.x); a.y += w2 * bhi(v2.x); a.z += w2 * blo(v2.y); a.w += w2 * bhi(v2.y);
        a.x += w3 * blo(v3.x); a.y += w3 * bhi(v3.x); a.z += w3 * blo(v3.y); a.w += w3 * bhi(v3.y);
      }
      for (; e < e1; ++e) {
        float w = wn[e];
        uint2 v = *reinterpret_cast<const uint2*>(&base[(size_t)col[e] * NCOUT + lc]);
        a.x += w * blo(v.x); a.y += w * bhi(v.x); a.z += w * blo(v.y); a.w += w * bhi(v.y);
      }
      uint2 o = {pk2(a.x, a.y), pk2(a.z, a.w)};
      *reinterpret_cast<uint2*>(&agg2[((size_t)g * LNODES + d) * NCOUT + lc]) = o;
      s.x += a.x; s.y += a.y; s.z += a.z; s.w += a.w;
      qq.x += a.x * a.x; qq.y += a.y * a.y; qq.z += a.z * a.z; qq.w += a.w * a.w;
    }
    *reinterpret_cast<float4*>(&lsum[wv][lc]) = s;
    *reinterpret_cast<float4*>(&lsq[wv][lc]) = qq;
    float4 z4 = {0.f, 0.f, 0.f, 0.f};
    *reinterpret_cast<float4*>(&lsum[wv + 4][lc]) = z4;
    *reinterpret_cast<float4*>(&lsq[wv + 4][lc]) = z4;
    sumO = st + 4096; sqO = st + 6144; shard = (b2 & 7) * NCOUT;
  }
  __syncthreads();
  float ts = 0.f, tq = 0.f;
#pragma unroll
  for (int r = 0; r < 8; ++r) {
    ts += lsum[r][t];
    tq += lsq[r][t];
  }
  atomicAdd(&sumO[shard + t], ts);
  atomicAdd(&sqO[shard + t], tq);
}

// ---------------- layer 2: fuse + transpose to channel-major fp32 d_out ----------------
__global__ __launch_bounds__(256) void fuse_tr_bf_k(const u16* __restrict__ A1,
                                                    const u16* __restrict__ A2,
                                                    const float* __restrict__ st,
                                                    const float* __restrict__ ga,
                                                    const float* __restrict__ be,
                                                    const float* __restrict__ gs,
                                                    const float* __restrict__ bes,
                                                    float* __restrict__ O) {
  __shared__ float T[64][65];  // [node_local][co_local]
  __shared__ float lk1[NCOUT], lk2[NCOUT], lcc[NCOUT];
  const int g = blockIdx.z;
  const int d0 = blockIdx.x * 64;
  const int c0 = blockIdx.y * 64;
  const int b = g >> 3;
  const int t = threadIdx.x;
  coef_ld(st, ga, be, gs, bes, lk1, lk2, lcc, t);
  __syncthreads();
  const int tr = t >> 4;
  const int tc = (t & 15) * 4;
#pragma unroll
  for (int p = 0; p < 4; ++p) {
    int d = d0 + tr + p * 16;
    uint2 a1 = *reinterpret_cast<const uint2*>(&A1[((size_t)g * LNODES + d) * NCOUT + c0 + tc]);
    uint2 a2 = *reinterpret_cast<const uint2*>(&A2[((size_t)b * LNODES + d) * NCOUT + c0 + tc]);
    int cb = c0 + tc;
    T[tr + p * 16][tc + 0] = fmaxf(lk1[cb+0] * blo(a1.x) + lk2[cb+0] * blo(a2.x) + lcc[cb+0], 0.f);
    T[tr + p * 16][tc + 1] = fmaxf(lk1[cb+1] * bhi(a1.x) + lk2[cb+1] * bhi(a2.x) + lcc[cb+1], 0.f);
    T[tr + p * 16][tc + 2] = fmaxf(lk1[cb+2] * blo(a1.y) + lk2[cb+2] * blo(a2.y) + lcc[cb+2], 0.f);
    T[tr + p * 16][tc + 3] = fmaxf(lk1[cb+3] * bhi(a1.y) + lk2[cb+3] * bhi(a2.y) + lcc[cb+3], 0.f);
  }
  __syncthreads();
#pragma unroll
  for (int p = 0; p < 4; ++p) {
    int c = tr + p * 16;
    float4 o = {T[tc + 0][c], T[tc + 1][c], T[tc + 2][c], T[tc + 3][c]};
    *reinterpret_cast<float4*>(&O[((size_t)g * NCOUT + c0 + c) * LNODES + d0 + tc]) = o;
  }
}

// ---------------- launch ----------------

extern "C" void kernel_launch(void* const* d_in, const int* in_sizes, int n_in,
                              void* d_out, int out_size, void* d_ws, size_t ws_size,
                              hipStream_t stream) {
  const float* x_in = (const float*)d_in[0];
  const int* ei = (const int*)d_in[1];
  const float* W[3]   = {(const float*)d_in[2],  (const float*)d_in[4],  (const float*)d_in[6]};
  const float* Wsym[3]= {(const float*)d_in[8],  (const float*)d_in[10], (const float*)d_in[12]};
  const float* ga[3]  = {(const float*)d_in[14], (const float*)d_in[16], (const float*)d_in[18]};
  const float* be[3]  = {(const float*)d_in[15], (const float*)d_in[17], (const float*)d_in[19]};
  const float* gs[3]  = {(const float*)d_in[20], (const float*)d_in[22], (const float*)d_in[24]};
  const float* bes[3] = {(const float*)d_in[21], (const float*)d_in[23], (const float*)d_in[25]};

  const size_t EBIG = (size_t)GBIG * LNODES * NCOUT;  // 16.7M elems
  const size_t ESM = (size_t)GSM * LNODES * NCOUT;
  char* p = (char*)d_ws;
  u16* XT0  = (u16*)p; p += (size_t)GBIG * LNODES * 128 * 2;  // 16 MiB layer-0 input
  u16* AGG1 = (u16*)p; p += EBIG * 2;   // 32 MiB
  u16* agg2 = (u16*)p; p += ESM * 2;    // 4 MiB
  u16* hw2  = (u16*)p; p += ESM * 2;    // 4 MiB
  u16* WbT[3], *WsT[3];
  for (int i = 0; i < 3; ++i) { WbT[i] = (u16*)p; p += NCOUT * NCOUT * 2; }
  for (int i = 0; i < 3; ++i) { WsT[i] = (u16*)p; p += NCOUT * NCOUT * 2; }
  int*   rp   = (int*)p;   p += 2064 * 4;
  float* dis  = (float*)p; p += LNODES * 4;
  float* selfn= (float*)p; p += LNODES * 4;
  char* zbase = p;
  float* deg  = (float*)p; p += LNODES * 4;
  int*   cnt  = (int*)p;   p += LNODES * 4;
  int*   fillc= (int*)p;   p += LNODES * 4;
  int*   col  = (int*)p;   p += (NEDGE + 8) * 4;  // padded, zeroed
  float* wn   = (float*)p; p += (NEDGE + 8) * 4;  // padded, zeroed
  float* stats= (float*)p; p += 3 * 4 * 2048 * 4; // [3 layers][sum1|sq1|sum2|sq2][8][256]
  size_t zsize = (size_t)(p - zbase);

  u16* HW1 = (u16*)d_out;  // big GEMM out in d_out (dead by fuse_tr time)
  float* stL[3] = {stats, stats + 8192, stats + 16384};

  // ---- setup: CSR + weights + input transpose (merged, 4 dispatches) ----
  hipMemsetAsync(zbase, 0, zsize, stream);
  WCvt wc;
  for (int i = 0; i < 3; ++i) {
    wc.src[i] = W[i];     wc.dst[i] = WbT[i];     wc.ci[i] = (i == 0) ? 128 : 256;
    wc.src[3 + i] = Wsym[i]; wc.dst[3 + i] = WsT[i]; wc.ci[3 + i] = (i == 0) ? 128 : 256;
  }
  setup1_k<<<2208, 256, 0, stream>>>(ei, deg, cnt, wc, x_in, XT0);
  setup2_k<<<9, 256, 0, stream>>>(deg, dis, selfn, cnt, rp);
  setup3_k<<<64, 256, 0, stream>>>(ei, rp, fillc, dis, col, wn);

  dim3 ggrid(LNODES / 64, 1, GBIG + GSM);
  // layer 0 (sym pool fused into staging)
  gemm3_k<0><<<ggrid, 256, 0, stream>>>(XT0, nullptr, nullptr, nullptr, nullptr, nullptr,
                                        nullptr, WbT[0], WsT[0], HW1, hw2);
  agg_comb_k<<<1280, 256, 0, stream>>>(HW1, hw2, col, wn, rp, selfn, AGG1, agg2, stL[0]);
  // layer 1 (BN+ReLU fuse of layer-0 agg happens inside B-staging)
  gemm3_k<1><<<ggrid, 256, 0, stream>>>(AGG1, agg2, stL[0], ga[0], be[0], gs[0], bes[0],
                                        WbT[1], WsT[1], HW1, hw2);
  agg_comb_k<<<1280, 256, 0, stream>>>(HW1, hw2, col, wn, rp, selfn, AGG1, agg2, stL[1]);
  // layer 2
  gemm3_k<1><<<ggrid, 256, 0, stream>>>(AGG1, agg2, stL[1], ga[1], be[1], gs[1], bes[1],
                                        WbT[2], WsT[2], HW1, hw2);
  agg_comb_k<<<1280, 256, 0, stream>>>(HW1, hw2, col, wn, rp, selfn, AGG1, agg2, stL[2]);
  fuse_tr_bf_k<<<dim3(LNODES / 64, NCOUT / 64, GBIG), 256, 0, stream>>>(
      AGG1, agg2, stL[2], ga[2], be[2], gs[2], bes[2], (float*)d_out);
}